// Round 4
// baseline (615.530 us; speedup 1.0000x reference)
//
#include <hip/hip_runtime.h>
#include <math.h>

#define N 4096
#define NHEAD 4
#define SPLIT_ATT 8
#define SPLIT_G 8

// ------------------------------------------------------------------
// enc1: H1 = relu(LN(X[N,256] @ W[256,512] + b))
__global__ __launch_bounds__(512) void k_enc1(const float* __restrict__ X,
    const float* __restrict__ W, const float* __restrict__ b,
    const float* __restrict__ g, const float* __restrict__ be,
    float* __restrict__ out) {
  __shared__ float xs[8][256];
  __shared__ float hs[8][512];
  const int t = threadIdx.x;
  const int row0 = blockIdx.x * 8;
  {
    const float4* src = reinterpret_cast<const float4*>(X + row0 * 256);
    float4* dst = reinterpret_cast<float4*>(&xs[0][0]);
    dst[t] = src[t];  // 512 float4 = 2048 floats
  }
  __syncthreads();
  float acc[8] = {0.f,0.f,0.f,0.f,0.f,0.f,0.f,0.f};
  for (int k = 0; k < 256; ++k) {
    float w = W[k * 512 + t];
#pragma unroll
    for (int r = 0; r < 8; ++r) acc[r] = fmaf(xs[r][k], w, acc[r]);
  }
  const float bb = b[t];
#pragma unroll
  for (int r = 0; r < 8; ++r) hs[r][t] = acc[r] + bb;
  __syncthreads();
  const int wv = t >> 6, lane = t & 63;
  float v0[8];
  float s1 = 0.f, s2 = 0.f;
#pragma unroll
  for (int kk = 0; kk < 8; ++kk) {
    float x = hs[wv][lane + 64 * kk];
    v0[kk] = x; s1 += x; s2 += x * x;
  }
#pragma unroll
  for (int off = 1; off < 64; off <<= 1) { s1 += __shfl_xor(s1, off); s2 += __shfl_xor(s2, off); }
  const float mean = s1 * (1.f / 512.f);
  const float var = s2 * (1.f / 512.f) - mean * mean;
  const float rstd = rsqrtf(var + 1e-5f);
#pragma unroll
  for (int kk = 0; kk < 8; ++kk) {
    int c = lane + 64 * kk;
    float y = g[c] * (v0[kk] - mean) * rstd + be[c];
    out[(row0 + wv) * 512 + c] = fmaxf(y, 0.f);
  }
}

// ------------------------------------------------------------------
// enc2: EMB = LN(H1[N,512] @ W[512,128] + b)
__global__ __launch_bounds__(128) void k_enc2(const float* __restrict__ X,
    const float* __restrict__ W, const float* __restrict__ b,
    const float* __restrict__ g, const float* __restrict__ be,
    float* __restrict__ out) {
  __shared__ float xs[8][512];
  __shared__ float hs[8][128];
  const int t = threadIdx.x;
  const int row0 = blockIdx.x * 8;
  {
    const float4* src = reinterpret_cast<const float4*>(X + row0 * 512);
    float4* dst = reinterpret_cast<float4*>(&xs[0][0]);
    for (int idx = t; idx < 1024; idx += 128) dst[idx] = src[idx];
  }
  __syncthreads();
  float acc[8] = {0.f,0.f,0.f,0.f,0.f,0.f,0.f,0.f};
  for (int k = 0; k < 512; ++k) {
    float w = W[k * 128 + t];
#pragma unroll
    for (int r = 0; r < 8; ++r) acc[r] = fmaf(xs[r][k], w, acc[r]);
  }
  const float bb = b[t];
#pragma unroll
  for (int r = 0; r < 8; ++r) hs[r][t] = acc[r] + bb;
  __syncthreads();
  const int wv = t >> 6, lane = t & 63;
  for (int rr = 0; rr < 4; ++rr) {
    int row = wv * 4 + rr;
    float a0 = hs[row][lane], a1 = hs[row][lane + 64];
    float s1 = a0 + a1, s2 = a0 * a0 + a1 * a1;
#pragma unroll
    for (int off = 1; off < 64; off <<= 1) { s1 += __shfl_xor(s1, off); s2 += __shfl_xor(s2, off); }
    float mean = s1 * (1.f / 128.f);
    float rstd = rsqrtf(s2 * (1.f / 128.f) - mean * mean + 1e-5f);
    out[(row0 + row) * 128 + lane]      = g[lane] * (a0 - mean) * rstd + be[lane];
    out[(row0 + row) * 128 + lane + 64] = g[lane + 64] * (a1 - mean) * rstd + be[lane + 64];
  }
}

// ------------------------------------------------------------------
// qkv: Q/K/V = EMB @ Wq/Wk/Wv
__global__ __launch_bounds__(128) void k_qkv(const float* __restrict__ emb,
    const float* __restrict__ Wq, const float* __restrict__ Wk, const float* __restrict__ Wv,
    float* __restrict__ q, float* __restrict__ k, float* __restrict__ v) {
  __shared__ float xs[8][128];
  const int t = threadIdx.x;
  const int row0 = blockIdx.x * 8;
  {
    const float4* src = reinterpret_cast<const float4*>(emb + row0 * 128);
    float4* dst = reinterpret_cast<float4*>(&xs[0][0]);
    for (int idx = t; idx < 256; idx += 128) dst[idx] = src[idx];
  }
  __syncthreads();
  float aq[8] = {0.f,0.f,0.f,0.f,0.f,0.f,0.f,0.f};
  float ak[8] = {0.f,0.f,0.f,0.f,0.f,0.f,0.f,0.f};
  float av[8] = {0.f,0.f,0.f,0.f,0.f,0.f,0.f,0.f};
  for (int kk = 0; kk < 128; ++kk) {
    float wq = Wq[kk * 128 + t], wk = Wk[kk * 128 + t], wv = Wv[kk * 128 + t];
#pragma unroll
    for (int r = 0; r < 8; ++r) {
      float x = xs[r][kk];
      aq[r] = fmaf(x, wq, aq[r]);
      ak[r] = fmaf(x, wk, ak[r]);
      av[r] = fmaf(x, wv, av[r]);
    }
  }
#pragma unroll
  for (int r = 0; r < 8; ++r) {
    q[(row0 + r) * 128 + t] = aq[r];
    k[(row0 + r) * 128 + t] = ak[r];
    v[(row0 + r) * 128 + t] = av[r];
  }
}

// ------------------------------------------------------------------
// ti[i] = sum_e tanh(temps[i,:] @ tW[:,e] + tb[e]) * wa[e]
// 4 lanes per row, each covers 32 of the 128 e's.
__global__ __launch_bounds__(256) void k_ti(const float* __restrict__ temps,
    const float* __restrict__ tW, const float* __restrict__ tb,
    const float* __restrict__ wa, float* __restrict__ ti_out) {
  __shared__ float tws[1280];
  __shared__ float tbs[128], was[128];
  const int t = threadIdx.x;
  for (int idx = t; idx < 1280; idx += 256) tws[idx] = tW[idx];
  if (t < 128) { tbs[t] = tb[t]; was[t] = wa[t]; }
  __syncthreads();
  const int qi = t & 3;           // e-quarter
  const int li = t >> 2;          // row within block
  const int i = blockIdx.x * 64 + li;
  float tp[10];
#pragma unroll
  for (int c = 0; c < 10; ++c) tp[c] = temps[i * 10 + c];
  float acc = 0.f;
  const int e0 = qi * 32;
  for (int e = e0; e < e0 + 32; ++e) {
    float s = tbs[e];
#pragma unroll
    for (int c = 0; c < 10; ++c) s = fmaf(tp[c], tws[c * 128 + e], s);
    // tanh(s) = 1 - 2/(exp(2s)+1)
    float th = 1.f - 2.f * __fdividef(1.f, __expf(2.f * s) + 1.f);
    acc = fmaf(th, was[e], acc);
  }
  acc += __shfl_xor(acc, 1);
  acc += __shfl_xor(acc, 2);
  if (qi == 0) ti_out[i] = acc;
}

// ------------------------------------------------------------------
// flash attention partial, additive adjacency|eye mask.
// Block = 256 thr: wave = head (4), lane = i-row (64-row i-tile).
// Full 32-dim dot per lane; K/V reads are wave-uniform LDS broadcasts.
// j-range N/SPLIT_ATT per block, tiles of 32 j.
__global__ __launch_bounds__(256, 2) void k_attn(const float* __restrict__ q,
    const float* __restrict__ kk, const float* __restrict__ vv,
    const int* __restrict__ adj, float* __restrict__ pacc, float* __restrict__ pml) {
  __shared__ float Kt[32][128];
  __shared__ float Vt[32][128];
  __shared__ float Mt[64][33];   // 0.f (allowed) or -1e9f (masked); stride 33 -> 2-way banks (free)
  const int t = threadIdx.x;
  const int itile = blockIdx.x / SPLIT_ATT;
  const int split = blockIdx.x % SPLIT_ATT;
  const int h = t >> 6;          // wave index = head
  const int row = t & 63;        // lane = row within 64-row tile
  const int i = itile * 64 + row;
  const int dbase = h * 32;
  float4 q4[8];
  {
    const float4* qp = reinterpret_cast<const float4*>(q + (size_t)i * 128 + dbase);
#pragma unroll
    for (int u = 0; u < 8; ++u) q4[u] = qp[u];
  }
  float m = -1e30f, l = 0.f;
  float4 a[8];
#pragma unroll
  for (int u = 0; u < 8; ++u) a[u] = make_float4(0.f, 0.f, 0.f, 0.f);
  const int j0beg = split * (N / SPLIT_ATT);
  const int j0end = j0beg + (N / SPLIT_ATT);
  for (int j0 = j0beg; j0 < j0end; j0 += 32) {
    __syncthreads();
    {
      const float4* ks = reinterpret_cast<const float4*>(kk + (size_t)j0 * 128);
      const float4* vs = reinterpret_cast<const float4*>(vv + (size_t)j0 * 128);
      float4* kd = reinterpret_cast<float4*>(&Kt[0][0]);
      float4* vd = reinterpret_cast<float4*>(&Vt[0][0]);
#pragma unroll
      for (int u = 0; u < 4; ++u) { kd[t + 256 * u] = ks[t + 256 * u]; vd[t + 256 * u] = vs[t + 256 * u]; }
    }
    {
      const int rr = t >> 2;            // 0..63
      const int c8 = (t & 3) * 8;       // 0,8,16,24
      const int gi = itile * 64 + rr;
      const int base = j0 + c8;
      const int4 a4 = *reinterpret_cast<const int4*>(adj + (size_t)gi * N + base);
      const int4 b4 = *reinterpret_cast<const int4*>(adj + (size_t)gi * N + base + 4);
      Mt[rr][c8 + 0] = (a4.x != 0 || gi == base + 0) ? 0.f : -1e9f;
      Mt[rr][c8 + 1] = (a4.y != 0 || gi == base + 1) ? 0.f : -1e9f;
      Mt[rr][c8 + 2] = (a4.z != 0 || gi == base + 2) ? 0.f : -1e9f;
      Mt[rr][c8 + 3] = (a4.w != 0 || gi == base + 3) ? 0.f : -1e9f;
      Mt[rr][c8 + 4] = (b4.x != 0 || gi == base + 4) ? 0.f : -1e9f;
      Mt[rr][c8 + 5] = (b4.y != 0 || gi == base + 5) ? 0.f : -1e9f;
      Mt[rr][c8 + 6] = (b4.z != 0 || gi == base + 6) ? 0.f : -1e9f;
      Mt[rr][c8 + 7] = (b4.w != 0 || gi == base + 7) ? 0.f : -1e9f;
    }
    __syncthreads();
    const float* mrow = Mt[row];
    for (int jj = 0; jj < 32; ++jj) {
      float4 kf[8];
      {
        const float4* kp = reinterpret_cast<const float4*>(&Kt[jj][dbase]);
#pragma unroll
        for (int u = 0; u < 8; ++u) kf[u] = kp[u];
      }
      float s0 = 0.f, s1 = 0.f, s2 = 0.f, s3 = 0.f;   // 4 chains of 8 for ILP
#pragma unroll
      for (int u = 0; u < 8; ++u) {
        s0 = fmaf(q4[u].x, kf[u].x, s0);
        s1 = fmaf(q4[u].y, kf[u].y, s1);
        s2 = fmaf(q4[u].z, kf[u].z, s2);
        s3 = fmaf(q4[u].w, kf[u].w, s3);
      }
      float s = fmaf((s0 + s1) + (s2 + s3), 0.17677669529663687f, mrow[jj]);
      float4 vf[8];
      {
        const float4* vp = reinterpret_cast<const float4*>(&Vt[jj][dbase]);
#pragma unroll
        for (int u = 0; u < 8; ++u) vf[u] = vp[u];
      }
      if (s <= m) {
        float p = __expf(s - m);
        l += p;
#pragma unroll
        for (int u = 0; u < 8; ++u) {
          a[u].x = fmaf(p, vf[u].x, a[u].x);
          a[u].y = fmaf(p, vf[u].y, a[u].y);
          a[u].z = fmaf(p, vf[u].z, a[u].z);
          a[u].w = fmaf(p, vf[u].w, a[u].w);
        }
      } else {
        float r = __expf(m - s);
        l = fmaf(l, r, 1.f);
        m = s;
#pragma unroll
        for (int u = 0; u < 8; ++u) {     // acc = acc*r + 1.0*v  (p_new = exp(0) = 1)
          a[u].x = fmaf(a[u].x, r, vf[u].x);
          a[u].y = fmaf(a[u].y, r, vf[u].y);
          a[u].z = fmaf(a[u].z, r, vf[u].z);
          a[u].w = fmaf(a[u].w, r, vf[u].w);
        }
      }
    }
  }
  {
    float4* pa4 = reinterpret_cast<float4*>(pacc + ((size_t)split * N + i) * 128 + dbase);
#pragma unroll
    for (int u = 0; u < 8; ++u) pa4[u] = a[u];
  }
  {
    // each thread owns a unique (i, h)
    float2* p2 = reinterpret_cast<float2*>(pml + (((size_t)split * N + i) * NHEAD + h) * 2);
    *p2 = make_float2(m, l);
  }
}

// combine attention partials across SPLIT_ATT
__global__ __launch_bounds__(256) void k_attn_comb(const float* __restrict__ pacc,
    const float* __restrict__ pml, float* __restrict__ attnout) {
  const int gid = blockIdx.x * 256 + threadIdx.x;  // over N*128
  const int i = gid >> 7, e = gid & 127, h = e >> 5;
  float ms[SPLIT_ATT], ls[SPLIT_ATT];
  float M = -1e30f;
#pragma unroll
  for (int s = 0; s < SPLIT_ATT; ++s) {
    size_t idx = (((size_t)s * N + i) * NHEAD + h) * 2;
    ms[s] = pml[idx]; ls[s] = pml[idx + 1];
    M = fmaxf(M, ms[s]);
  }
  float L = 0.f, o = 0.f;
#pragma unroll
  for (int s = 0; s < SPLIT_ATT; ++s) {
    float w = expf(ms[s] - M);    // dead/masked splits: exp(-1e9 - M) == 0 exactly
    L = fmaf(ls[s], w, L);
    o = fmaf(pacc[((size_t)(s * N + i)) * 128 + e], w, o);
  }
  attnout[gid] = o / L;
}

// ------------------------------------------------------------------
// ctx = attnout @ Wo ; cj = ctx @ gate_wb
__global__ __launch_bounds__(128) void k_ctx(const float* __restrict__ att,
    const float* __restrict__ Wo, const float* __restrict__ wb,
    float* __restrict__ ctx, float* __restrict__ cj) {
  __shared__ float xs[8][128];
  __shared__ float hs[8][128];
  const int t = threadIdx.x;
  const int row0 = blockIdx.x * 8;
  {
    const float4* src = reinterpret_cast<const float4*>(att + row0 * 128);
    float4* dst = reinterpret_cast<float4*>(&xs[0][0]);
    for (int idx = t; idx < 256; idx += 128) dst[idx] = src[idx];
  }
  __syncthreads();
  float acc[8] = {0.f,0.f,0.f,0.f,0.f,0.f,0.f,0.f};
  for (int k = 0; k < 128; ++k) {
    float w = Wo[k * 128 + t];
#pragma unroll
    for (int r = 0; r < 8; ++r) acc[r] = fmaf(xs[r][k], w, acc[r]);
  }
  const float wbt = wb[t];
#pragma unroll
  for (int r = 0; r < 8; ++r) {
    ctx[(row0 + r) * 128 + t] = acc[r];
    hs[r][t] = acc[r] * wbt;
  }
  __syncthreads();
  const int wv = t >> 6, lane = t & 63;
  for (int rr = 0; rr < 4; ++rr) {
    int row = wv * 4 + rr;
    float s1 = hs[row][lane] + hs[row][lane + 64];
#pragma unroll
    for (int off = 1; off < 64; off <<= 1) s1 += __shfl_xor(s1, off);
    if (lane == 0) cj[row0 + row] = s1;
  }
}

// ------------------------------------------------------------------
// gate partial v2 (register-tiled GEMM):
//   acc[i,e] = sum_j nmask(i,j) * sigmoid(ti[i]+cj[j]+gb) * ctx[j,e]
// Block: i-tile 64 rows, j-range N/SPLIT_G in tiles of 64.
// Thread tile 4i x 8e (256 thr = 16 i-groups x 16 e-groups).
// Gates built per j-tile into transposed gtsT[jj][ii] (pad 65).
// Neighbor counts accumulated in the BUILD phase (mask-based, exact),
// so the inner loop is a pure on-the-fly GEMM: 6 LDS + 32 FMA per jj.
__global__ __launch_bounds__(256) void k_gate(const float* __restrict__ ctx,
    const float* __restrict__ cj, const float* __restrict__ ti,
    const int* __restrict__ adj, const float* __restrict__ gbp,
    float* __restrict__ pacc, float* __restrict__ pcnt) {
  __shared__ float cs[64][128];    // ctx tile, j-major
  __shared__ float gtsT[64][65];   // gate, transposed [jj][ii]; pad 65 -> 2-way writes (free)
  __shared__ float tis[64];
  __shared__ float cntrow[64];     // running neighbor count per row (thread t owns cntrow[t])
  __shared__ float pcsum[256];     // per-thread per-tile mask counts
  const int t = threadIdx.x;
  const int itile = blockIdx.x >> 3;     // SPLIT_G = 8
  const int split = blockIdx.x & 7;
  const int ig = t >> 4;                 // 0..15 -> rows ig*4 .. ig*4+3
  const int eg = t & 15;                 // 0..15 -> cols eg*8 .. eg*8+7
  const int i0 = itile * 64;
  const float gb = gbp[0];
  if (t < 64) { tis[t] = ti[i0 + t]; cntrow[t] = 0.f; }
  float acc[4][8];
#pragma unroll
  for (int r = 0; r < 4; ++r)
#pragma unroll
    for (int c = 0; c < 8; ++c) acc[r][c] = 0.f;
  const int j0beg = split * (N / SPLIT_G);
  const int j0end = j0beg + (N / SPLIT_G);
  for (int j0 = j0beg; j0 < j0end; j0 += 64) {
    __syncthreads();   // protect cs/gtsT/pcsum from previous tile's readers (and tis init)
    {  // stage ctx tile: 64x128 = 2048 float4 / 256 thr = 8 each
      const float4* src = reinterpret_cast<const float4*>(ctx + (size_t)j0 * 128);
      float4* dst = reinterpret_cast<float4*>(&cs[0][0]);
#pragma unroll
      for (int u = 0; u < 8; ++u) dst[t + 256 * u] = src[t + 256 * u];
    }
    {  // build gates: thread handles row ii = t>>2, 16 consecutive jj
      const int ii = t >> 2;
      const int jb = (t & 3) * 16;
      const int gi = i0 + ii;
      const float tii = tis[ii];
      const int gjb = j0 + jb;
      float cnt_loc = 0.f;
#pragma unroll
      for (int u = 0; u < 4; ++u) {
        const int4 a4 = *reinterpret_cast<const int4*>(adj + (size_t)gi * N + gjb + u * 4);
        const float4 c4 = *reinterpret_cast<const float4*>(cj + gjb + u * 4);
        const int   aa[4] = {a4.x, a4.y, a4.z, a4.w};
        const float cc[4] = {c4.x, c4.y, c4.z, c4.w};
#pragma unroll
        for (int w = 0; w < 4; ++w) {
          const int jj = jb + u * 4 + w;
          const bool live = (aa[w] != 0) && (gjb + u * 4 + w != gi);
          float gval = 0.f;
          if (live) {
            gval = __fdividef(1.f, 1.f + __expf(-(tii + cc[w] + gb)));
            cnt_loc += 1.f;
          }
          gtsT[jj][ii] = gval;
        }
      }
      pcsum[t] = cnt_loc;
    }
    __syncthreads();   // build complete
    if (t < 64) {      // fold this tile's mask counts into the running per-row count
      cntrow[t] += pcsum[t * 4] + pcsum[t * 4 + 1] + pcsum[t * 4 + 2] + pcsum[t * 4 + 3];
    }
    // inner GEMM: 64 jj x (4 A-broadcast b32 + 2 B b128 + 32 FMA)
    const int ib = ig * 4;
    const int eb = eg * 8;
    for (int jj = 0; jj < 64; ++jj) {
      const float a0 = gtsT[jj][ib + 0];
      const float a1 = gtsT[jj][ib + 1];
      const float a2 = gtsT[jj][ib + 2];
      const float a3 = gtsT[jj][ib + 3];
      const float4 b0 = *reinterpret_cast<const float4*>(&cs[jj][eb]);
      const float4 b1 = *reinterpret_cast<const float4*>(&cs[jj][eb + 4]);
      const float bv[8] = {b0.x, b0.y, b0.z, b0.w, b1.x, b1.y, b1.z, b1.w};
#pragma unroll
      for (int c = 0; c < 8; ++c) {
        acc[0][c] = fmaf(a0, bv[c], acc[0][c]);
        acc[1][c] = fmaf(a1, bv[c], acc[1][c]);
        acc[2][c] = fmaf(a2, bv[c], acc[2][c]);
        acc[3][c] = fmaf(a3, bv[c], acc[3][c]);
      }
    }
  }
  // epilogue
#pragma unroll
  for (int r = 0; r < 4; ++r) {
    float* pa = pacc + ((size_t)split * N + i0 + ig * 4 + r) * 128 + eg * 8;
    float4 o0; o0.x = acc[r][0]; o0.y = acc[r][1]; o0.z = acc[r][2]; o0.w = acc[r][3];
    float4 o1; o1.x = acc[r][4]; o1.y = acc[r][5]; o1.z = acc[r][6]; o1.w = acc[r][7];
    reinterpret_cast<float4*>(pa)[0] = o0;
    reinterpret_cast<float4*>(pa)[1] = o1;
  }
  if (t < 64) pcnt[(size_t)split * N + i0 + t] = cntrow[t];
}

// gate combine + updated + generational memory retrieval
__global__ __launch_bounds__(256) void k_gcomb(const float* __restrict__ GA,
    const float* __restrict__ GC, const float* __restrict__ emb,
    const float* __restrict__ mb, float* __restrict__ upd) {
  __shared__ float mbs[10][128];
  __shared__ float us[2][128];
  const int t = threadIdx.x;
  for (int idx = t; idx < 1280; idx += 256) mbs[idx / 128][idx & 127] = mb[idx];
  const int rs = t >> 7, e = t & 127;
  const int i = blockIdx.x * 2 + rs;
  float a = 0.f;
#pragma unroll
  for (int s = 0; s < SPLIT_G; ++s) a += GA[((size_t)(s * N + i)) * 128 + e];
  float c = 0.f;
#pragma unroll
  for (int s = 0; s < SPLIT_G; ++s) c += GC[s * N + i];
  float comb = a / fmaxf(c, 1.f);
  float u = emb[(size_t)i * 128 + e] + 0.2f * ((c > 0.f) ? comb : 0.f);
  us[rs][e] = u;
  __syncthreads();
  const int wv = t >> 6, lane = t & 63;
  if (wv < 2) {
    const int i2 = blockIdx.x * 2 + wv;
    float u0 = us[wv][lane], u1 = us[wv][lane + 64];
    float sc[10];
#pragma unroll
    for (int g = 0; g < 10; ++g) {
      float p = u0 * mbs[g][lane] + u1 * mbs[g][lane + 64];
#pragma unroll
      for (int off = 1; off < 64; off <<= 1) p += __shfl_xor(p, off);
      sc[g] = p * 0.08838834764831845f;  // 1/sqrt(128)
    }
    float mx = sc[0];
#pragma unroll
    for (int g = 1; g < 10; ++g) mx = fmaxf(mx, sc[g]);
    float sum = 0.f;
#pragma unroll
    for (int g = 0; g < 10; ++g) { sc[g] = expf(sc[g] - mx); sum += sc[g]; }
    float inv = 1.f / sum;
    float anc0 = 0.f, anc1 = 0.f;
#pragma unroll
    for (int g = 0; g < 10; ++g) {
      float pg = sc[g] * inv;
      anc0 = fmaf(pg, mbs[g][lane], anc0);
      anc1 = fmaf(pg, mbs[g][lane + 64], anc1);
    }
    upd[(size_t)i2 * 128 + lane]      = 0.9f * u0 + 0.1f * anc0;
    upd[(size_t)i2 * 128 + lane + 64] = 0.9f * u1 + 0.1f * anc1;
  }
}

// ------------------------------------------------------------------
// dec1: D = relu(LN(UPD[N,128] @ W[128,512] + b))
__global__ __launch_bounds__(512) void k_dec1(const float* __restrict__ X,
    const float* __restrict__ W, const float* __restrict__ b,
    const float* __restrict__ g, const float* __restrict__ be,
    float* __restrict__ out) {
  __shared__ float xs[8][128];
  __shared__ float hs[8][512];
  const int t = threadIdx.x;
  const int row0 = blockIdx.x * 8;
  if (t < 256) {
    const float4* src = reinterpret_cast<const float4*>(X + row0 * 128);
    float4* dst = reinterpret_cast<float4*>(&xs[0][0]);
    dst[t] = src[t];
  }
  __syncthreads();
  float acc[8] = {0.f,0.f,0.f,0.f,0.f,0.f,0.f,0.f};
  for (int k = 0; k < 128; ++k) {
    float w = W[k * 512 + t];
#pragma unroll
    for (int r = 0; r < 8; ++r) acc[r] = fmaf(xs[r][k], w, acc[r]);
  }
  const float bb = b[t];
#pragma unroll
  for (int r = 0; r < 8; ++r) hs[r][t] = acc[r] + bb;
  __syncthreads();
  const int wv = t >> 6, lane = t & 63;
  float v0[8];
  float s1 = 0.f, s2 = 0.f;
#pragma unroll
  for (int kk = 0; kk < 8; ++kk) {
    float x = hs[wv][lane + 64 * kk];
    v0[kk] = x; s1 += x; s2 += x * x;
  }
#pragma unroll
  for (int off = 1; off < 64; off <<= 1) { s1 += __shfl_xor(s1, off); s2 += __shfl_xor(s2, off); }
  const float mean = s1 * (1.f / 512.f);
  const float var = s2 * (1.f / 512.f) - mean * mean;
  const float rstd = rsqrtf(var + 1e-5f);
#pragma unroll
  for (int kk = 0; kk < 8; ++kk) {
    int c = lane + 64 * kk;
    float y = g[c] * (v0[kk] - mean) * rstd + be[c];
    out[(row0 + wv) * 512 + c] = fmaxf(y, 0.f);
  }
}

// dec2: out = D[N,512] @ W[512,256] + b
__global__ __launch_bounds__(256) void k_dec2(const float* __restrict__ X,
    const float* __restrict__ W, const float* __restrict__ b, float* __restrict__ out) {
  __shared__ float xs[8][512];
  const int t = threadIdx.x;
  const int row0 = blockIdx.x * 8;
  {
    const float4* src = reinterpret_cast<const float4*>(X + row0 * 512);
    float4* dst = reinterpret_cast<float4*>(&xs[0][0]);
    for (int idx = t; idx < 1024; idx += 256) dst[idx] = src[idx];
  }
  __syncthreads();
  float acc[8] = {0.f,0.f,0.f,0.f,0.f,0.f,0.f,0.f};
  for (int k = 0; k < 512; ++k) {
    float w = W[k * 256 + t];
#pragma unroll
    for (int r = 0; r < 8; ++r) acc[r] = fmaf(xs[r][k], w, acc[r]);
  }
  const float bb = b[t];
#pragma unroll
  for (int r = 0; r < 8; ++r) out[(row0 + r) * 256 + t] = acc[r] + bb;
}

// ------------------------------------------------------------------
extern "C" void kernel_launch(void* const* d_in, const int* in_sizes, int n_in,
                              void* d_out, int out_size, void* d_ws, size_t ws_size,
                              hipStream_t stream) {
  const float* lora   = (const float*)d_in[0];
  const float* temps  = (const float*)d_in[1];
  const int*   adj    = (const int*)d_in[2];
  const float* mb     = (const float*)d_in[3];
  const float* enc_W1 = (const float*)d_in[4];
  const float* enc_b1 = (const float*)d_in[5];
  const float* enc_g1 = (const float*)d_in[6];
  const float* enc_be1= (const float*)d_in[7];
  const float* enc_W2 = (const float*)d_in[8];
  const float* enc_b2 = (const float*)d_in[9];
  const float* enc_g2 = (const float*)d_in[10];
  const float* enc_be2= (const float*)d_in[11];
  const float* temp_W = (const float*)d_in[12];
  const float* temp_b = (const float*)d_in[13];
  const float* Wq     = (const float*)d_in[14];
  const float* Wk     = (const float*)d_in[15];
  const float* Wv     = (const float*)d_in[16];
  const float* Wo     = (const float*)d_in[17];
  const float* g_wa   = (const float*)d_in[18];
  const float* g_wb   = (const float*)d_in[19];
  const float* g_b    = (const float*)d_in[20];
  const float* dec_W1 = (const float*)d_in[21];
  const float* dec_b1 = (const float*)d_in[22];
  const float* dec_g1 = (const float*)d_in[23];
  const float* dec_be1= (const float*)d_in[24];
  const float* dec_W2 = (const float*)d_in[25];
  const float* dec_b2 = (const float*)d_in[26];

  float* ws = (float*)d_ws;
  float* H1  = ws;                      // N*512 (reused as DEC later)
  float* EMB = H1 + (size_t)N * 512;    // N*128
  float* Q   = EMB + (size_t)N * 128;
  float* K   = Q + (size_t)N * 128;
  float* V   = K + (size_t)N * 128;
  float* ATT = V + (size_t)N * 128;     // reused as UPD later
  float* CTX = ATT + (size_t)N * 128;
  float* TI  = CTX + (size_t)N * 128;   // N
  float* CJ  = TI + N;                  // N
  float* PA  = CJ + N;                  // 8*N*128 (reused as GA)
  float* PML = PA + (size_t)8 * N * 128;  // 8*N*NHEAD*2 (reused as GC, 8*N)
  float* UPD = ATT;
  float* GA  = PA;
  float* GC  = PML;
  float* DEC = H1;

  k_enc1<<<N / 8, 512, 0, stream>>>(lora, enc_W1, enc_b1, enc_g1, enc_be1, H1);
  k_enc2<<<N / 8, 128, 0, stream>>>(H1, enc_W2, enc_b2, enc_g2, enc_be2, EMB);
  k_ti<<<N / 64, 256, 0, stream>>>(temps, temp_W, temp_b, g_wa, TI);
  k_qkv<<<N / 8, 128, 0, stream>>>(EMB, Wq, Wk, Wv, Q, K, V);
  k_attn<<<(N / 64) * SPLIT_ATT, 256, 0, stream>>>(Q, K, V, adj, PA, PML);
  k_attn_comb<<<(N * 128) / 256, 256, 0, stream>>>(PA, PML, ATT);
  k_ctx<<<N / 8, 128, 0, stream>>>(ATT, Wo, g_wb, CTX, CJ);
  k_gate<<<(N / 64) * SPLIT_G, 256, 0, stream>>>(CTX, CJ, TI, adj, g_b, GA, GC);
  k_gcomb<<<N / 2, 256, 0, stream>>>(GA, GC, EMB, mb, UPD);
  k_dec1<<<N / 8, 512, 0, stream>>>(UPD, dec_W1, dec_b1, dec_g1, dec_be1, DEC);
  k_dec2<<<N / 8, 256, 0, stream>>>(DEC, dec_W2, dec_b2, (float*)d_out);
}